// Round 6
// baseline (333.639 us; speedup 1.0000x reference)
//
#include <hip/hip_runtime.h>

#define N_NODES 50000
#define N_EDGES 600000
#define E_PAD_MAX (N_EDGES + N_NODES * 7)   // padded edge capacity

using bf16x8 = __attribute__((ext_vector_type(8))) short;
using f32x4  = __attribute__((ext_vector_type(4))) float;
typedef unsigned int uint32_tt;

__device__ __forceinline__ unsigned short f2bf(float f) {
    union { float f; unsigned int u; } v; v.f = f;
    unsigned int u = v.u;
    return (unsigned short)((u + 0x7fffu + ((u >> 16) & 1u)) >> 16);  // RNE
}
__device__ __forceinline__ float bf2f(unsigned int h16) {
    union { unsigned int u; float f; } v; v.u = h16 << 16;
    return v.f;
}

// ---------------- CSR build (degrees padded to multiple of 8) ----------------

__global__ void hist_kernel(const int* __restrict__ ei, int* __restrict__ cnt, int E) {
    int e = blockIdx.x * 256 + threadIdx.x;
    if (e < E) atomicAdd(&cnt[ei[E + e]], 1);
}

// scan over PADDED degrees: (deg+7)&~7
__global__ void scan1(const int* __restrict__ deg, int* __restrict__ out,
                      int* __restrict__ bsum, int n) {
    __shared__ int s[256];
    int t = threadIdx.x;
    int base = blockIdx.x * 1024 + t * 4;
    int v0 = (base + 0 < n) ? ((deg[base + 0] + 7) & ~7) : 0;
    int v1 = (base + 1 < n) ? ((deg[base + 1] + 7) & ~7) : 0;
    int v2 = (base + 2 < n) ? ((deg[base + 2] + 7) & ~7) : 0;
    int v3 = (base + 3 < n) ? ((deg[base + 3] + 7) & ~7) : 0;
    int tsum = v0 + v1 + v2 + v3;
    s[t] = tsum;
    __syncthreads();
    for (int off = 1; off < 256; off <<= 1) {
        int tmp = (t >= off) ? s[t - off] : 0;
        __syncthreads();
        s[t] += tmp;
        __syncthreads();
    }
    int excl = s[t] - tsum;
    if (base + 0 < n) out[base + 0] = excl;
    if (base + 1 < n) out[base + 1] = excl + v0;
    if (base + 2 < n) out[base + 2] = excl + v0 + v1;
    if (base + 3 < n) out[base + 3] = excl + v0 + v1 + v2;
    if (t == 255) bsum[blockIdx.x] = s[255];
}

__global__ void scan2(int* __restrict__ bsum, int nb) {
    if (threadIdx.x == 0 && blockIdx.x == 0) {
        int acc = 0;
        for (int i = 0; i < nb; ++i) { int v = bsum[i]; bsum[i] = acc; acc += v; }
        bsum[nb] = acc;   // total padded edge count
    }
}

__global__ void scan3(int* __restrict__ off, const int* __restrict__ bsum, int n, int nb) {
    int i = blockIdx.x * 256 + threadIdx.x;
    if (i < n) off[i] += bsum[i >> 10];
    if (i == n) off[n] = bsum[nb];
}

// 8-byte edge record: {src:u32, bf16(cr)|bf16(ci)<<16}; pad slots stay all-zero
// from the edat memset ({src=0, cr=0, ci=0} contributes exactly 0)
__global__ void scatter_kernel(const int* __restrict__ ei, const float* __restrict__ w,
                               const float* __restrict__ sim, const int* __restrict__ off,
                               int* __restrict__ cnt, uint2* __restrict__ edat, int E) {
    int e = blockIdx.x * 256 + threadIdx.x;
    if (e >= E) return;
    int s = ei[e], d = ei[E + e];
    int p = off[d] + atomicAdd(&cnt[d], 1);
    float wt = w[e];
    uint2 m;
    m.x = (unsigned)s;
    m.y = (uint32_tt)f2bf(wt * sim[2 * e]) |
          ((uint32_tt)f2bf(wt * sim[2 * e + 1]) << 16);
    edat[p] = m;
}

// ---------------- prep: x -> bf16 padded [N][96]; weight packs ----------------

__global__ void convert_x(const float* __restrict__ x0, unsigned short* __restrict__ xb, int n) {
    int i = blockIdx.x * 256 + threadIdx.x;
    if (i >= n * 96) return;
    int r = i / 96, c = i - r * 96;
    xb[i] = (c < 75) ? f2bf(x0[r * 75 + c]) : (unsigned short)0;
}

// BT[n][part*CINP + k] = {wr[k][n], -wi[k][n], lw[n][k]}  (bf16, zero-padded k>=CIN)
__global__ void build_bt(const float* __restrict__ wr, const float* __restrict__ wi,
                         const float* __restrict__ lw, unsigned short* __restrict__ BT,
                         int CIN, int CINP, int COUT) {
    int KTOT = 3 * CINP;
    int i = blockIdx.x * 256 + threadIdx.x;
    if (i >= COUT * KTOT) return;
    int nn = i / KTOT, k = i - nn * KTOT;
    int part = k / CINP, kk = k - part * CINP;
    float v = 0.f;
    if (kk < CIN) {
        if (part == 0)      v = wr[kk * COUT + nn];
        else if (part == 1) v = -wi[kk * COUT + nn];
        else                v = lw[nn * CIN + kk];
    }
    BT[i] = f2bf(v);
}

// layer-2 projection weights: BTy [96][128]: rows 0-31 wr2 cols, 32-63 -wi2
// cols, 64-95 lw2 rows  =>  Y = h2 @ [wr2 | -wi2 | lw2^T]
__global__ void build_bty(const float* __restrict__ wr, const float* __restrict__ wi,
                          const float* __restrict__ lw, unsigned short* __restrict__ BT) {
    int i = blockIdx.x * 256 + threadIdx.x;
    if (i >= 96 * 128) return;
    int nn = i >> 7, k = i & 127;
    float v;
    if (nn < 32)      v = wr[k * 32 + nn];
    else if (nn < 64) v = -wi[k * 32 + (nn - 32)];
    else              v = lw[(nn - 64) * 128 + k];
    BT[i] = f2bf(v);
}

// ---------------- aggregation: one wave per node, scalarized edge metadata ---
template <int CU2>  // uint32s per feature row (= CINP/2)
__global__ __launch_bounds__(256) void agg_bf16(
    const uint32_tt* __restrict__ x, const int* __restrict__ off,
    const uint2* __restrict__ edat, uint32_tt* __restrict__ aggR,
    uint32_tt* __restrict__ aggI, int n) {
    int wave = threadIdx.x >> 6;
    int lane = threadIdx.x & 63;
    int node = __builtin_amdgcn_readfirstlane(blockIdx.x * 4 + wave);
    if (node >= n) return;
    int lc = (CU2 == 64) ? lane : (lane < CU2 ? lane : CU2 - 1);  // clamped lane
    float arl = 0.f, arh = 0.f, ail = 0.f, aih = 0.f;
    int e0 = __builtin_amdgcn_readfirstlane(off[node]);
    int e1 = __builtin_amdgcn_readfirstlane(off[node + 1]);

    if (e0 < e1) {
        uint2 m[8];
#pragma unroll
        for (int j = 0; j < 8; ++j) m[j] = edat[e0 + j];
        for (int e = e0; e < e1; e += 8) {
            int sj[8]; float crj[8], cij[8];
#pragma unroll
            for (int j = 0; j < 8; ++j) {
                sj[j] = __builtin_amdgcn_readfirstlane((int)m[j].x);
                int pk = __builtin_amdgcn_readfirstlane((int)m[j].y);
                crj[j] = bf2f((unsigned)pk & 0xffffu);
                cij[j] = bf2f((unsigned)pk >> 16);
            }
            // 8 independent gathers, SGPR base + invariant lane offset
            uint32_tt w[8];
#pragma unroll
            for (int j = 0; j < 8; ++j) {
                const uint32_tt* rowp = x + (size_t)sj[j] * CU2;
                w[j] = rowp[lc];
            }
            // prefetch next batch's metadata while gathers are in flight
            if (e + 8 < e1) {
#pragma unroll
                for (int j = 0; j < 8; ++j) m[j] = edat[e + 8 + j];
            }
#pragma unroll
            for (int j = 0; j < 8; ++j) {
                float lo = bf2f(w[j] & 0xffffu), hi = bf2f(w[j] >> 16);
                arl += crj[j] * lo; arh += crj[j] * hi;
                ail += cij[j] * lo; aih += cij[j] * hi;
            }
        }
    }
    if (lane < CU2) {
        aggR[(size_t)node * CU2 + lane] = (uint32_tt)f2bf(arl) | ((uint32_tt)f2bf(arh) << 16);
        aggI[(size_t)node * CU2 + lane] = (uint32_tt)f2bf(ail) | ((uint32_tt)f2bf(aih) << 16);
    }
}

// ---------------- layer-2 fused aggregate + bias + relu + store --------------
// Y [n][48 dwords]: dwords 0-31 = [yr(32 cols)|yin(32 cols)] bf16, 32-47 = lin.
// One wave per node, 2 edges per iteration (half-wave each, 128B gathers).
__global__ __launch_bounds__(256) void agg_out(
    const uint32_tt* __restrict__ Y, const int* __restrict__ off,
    const uint2* __restrict__ edat, const float* __restrict__ cb,
    const float* __restrict__ lb, float* __restrict__ out, int n) {
    int wave = threadIdx.x >> 6;
    int lane = threadIdx.x & 63;
    int node = __builtin_amdgcn_readfirstlane(blockIdx.x * 4 + wave);
    if (node >= n) return;
    int half = lane >> 5, sl = lane & 31;
    float alo = 0.f, ahi = 0.f;
    int e0 = __builtin_amdgcn_readfirstlane(off[node]);
    int e1 = __builtin_amdgcn_readfirstlane(off[node + 1]);

    if (e0 < e1) {
        uint2 m[8];
#pragma unroll
        for (int j = 0; j < 8; ++j) m[j] = edat[e0 + j];
        for (int e = e0; e < e1; e += 8) {
            int sj[8]; float crj[8], cij[8];
#pragma unroll
            for (int j = 0; j < 8; ++j) {
                sj[j] = __builtin_amdgcn_readfirstlane((int)m[j].x);
                int pk = __builtin_amdgcn_readfirstlane((int)m[j].y);
                crj[j] = bf2f((unsigned)pk & 0xffffu);
                cij[j] = bf2f((unsigned)pk >> 16);
            }
            uint32_tt w[4];
#pragma unroll
            for (int jj = 0; jj < 4; ++jj) {
                int s = half ? sj[2 * jj + 1] : sj[2 * jj];
                w[jj] = Y[(size_t)s * 48 + sl];
            }
            if (e + 8 < e1) {
#pragma unroll
                for (int j = 0; j < 8; ++j) m[j] = edat[e + 8 + j];
            }
#pragma unroll
            for (int jj = 0; jj < 4; ++jj) {
                float cr = half ? crj[2 * jj + 1] : crj[2 * jj];
                float ci = half ? cij[2 * jj + 1] : cij[2 * jj];
                float c = (sl < 16) ? cr : ci;
                float lo = bf2f(w[jj] & 0xffffu), hi = bf2f(w[jj] >> 16);
                alo += c * lo; ahi += c * hi;
            }
        }
    }
    // combine the two half-wave edge partials, then yr+yin partner lanes
    alo += __shfl_xor(alo, 32); ahi += __shfl_xor(ahi, 32);
    alo += __shfl_xor(alo, 16); ahi += __shfl_xor(ahi, 16);
    if (half == 0 && sl < 16) {
        uint32_tt lw_ = Y[(size_t)node * 48 + 32 + sl];
        int c0 = 2 * sl, c1 = 2 * sl + 1;
        float v0 = alo + bf2f(lw_ & 0xffffu) + cb[c0] + lb[c0];
        float v1 = ahi + bf2f(lw_ >> 16) + cb[c1] + lb[c1];
        out[(size_t)node * 32 + c0] = v0 > 0.f ? v0 : 0.f;
        out[(size_t)node * 32 + c1] = v1 > 0.f ? v1 : 0.f;
    }
}

// ---------------- bf16 MFMA GEMM ---------------------------------------------
// PARTS=3: out = relu([A0|A1|A2] @ BT^T + cb + lb); PARTS=1, RAW: out = A0 @ BT^T
template <int CINP, int COUT, int BM, int WM, int WN, int MT, int NT,
          bool OUT_BF16, bool RAW, int PARTS>
__global__ __launch_bounds__(256) void gemm_mfma(
    const unsigned short* __restrict__ A0, const unsigned short* __restrict__ A1,
    const unsigned short* __restrict__ A2, const unsigned short* __restrict__ BT,
    const float* __restrict__ cb, const float* __restrict__ lb,
    void* __restrict__ outv, int n) {
    constexpr int PK = 40;              // padded k-stride (bf16): 80B rows -> 2-way banks
    constexpr int KTOT = PARTS * CINP;
    constexpr int NCH = KTOT / 32;      // K chunks
    constexpr int CPP = CINP / 32;      // chunks per part
    __shared__ unsigned short sA[BM][PK];
    __shared__ unsigned short sB[COUT][PK];

    int t = threadIdx.x;
    int lane = t & 63, wave = t >> 6;
    int wm = wave / WN, wn = wave % WN;
    int ml = lane & 15, kh = lane >> 4;   // kh in [0,4)
    int node0 = blockIdx.x * BM;

    const unsigned short* Asrc[3] = {A0, A1, A2};

    f32x4 acc[MT][NT];
#pragma unroll
    for (int mt = 0; mt < MT; ++mt)
#pragma unroll
        for (int nt = 0; nt < NT; ++nt) acc[mt][nt] = (f32x4){0.f, 0.f, 0.f, 0.f};

    for (int c = 0; c < NCH; ++c) {
        int part = (PARTS == 1) ? 0 : (c / CPP);
        int kk = (c - part * CPP) * 32;
        const unsigned short* __restrict__ Ap = Asrc[part];
        __syncthreads();
#pragma unroll
        for (int i = t; i < BM * 4; i += 256) {
            int r = i >> 2, q = i & 3;
            int node = node0 + r;
            if (node >= n) node = n - 1;  // clamp: garbage rows never written out
            *(uint4*)&sA[r][q * 8] =
                *(const uint4*)(Ap + (size_t)node * CINP + kk + q * 8);
        }
#pragma unroll
        for (int i = t; i < COUT * 4; i += 256) {
            int r = i >> 2, q = i & 3;
            *(uint4*)&sB[r][q * 8] =
                *(const uint4*)(BT + (size_t)r * KTOT + c * 32 + q * 8);
        }
        __syncthreads();
        bf16x8 af[MT], bfr[NT];
#pragma unroll
        for (int mt = 0; mt < MT; ++mt)
            af[mt] = *(const bf16x8*)&sA[wm * (MT * 16) + mt * 16 + ml][kh * 8];
#pragma unroll
        for (int nt = 0; nt < NT; ++nt)
            bfr[nt] = *(const bf16x8*)&sB[wn * (NT * 16) + nt * 16 + ml][kh * 8];
#pragma unroll
        for (int mt = 0; mt < MT; ++mt)
#pragma unroll
            for (int nt = 0; nt < NT; ++nt)
                acc[mt][nt] = __builtin_amdgcn_mfma_f32_16x16x32_bf16(
                    af[mt], bfr[nt], acc[mt][nt], 0, 0, 0);
    }

    // epilogue: C/D layout col=lane&15, row=(lane>>4)*4+reg  [m89-verified]
    int row0 = kh * 4;
#pragma unroll
    for (int nt = 0; nt < NT; ++nt) {
        int col = wn * (NT * 16) + nt * 16 + ml;
        float bias = RAW ? 0.f : (cb[col] + lb[col]);
#pragma unroll
        for (int mt = 0; mt < MT; ++mt) {
#pragma unroll
            for (int r = 0; r < 4; ++r) {
                int node = node0 + wm * (MT * 16) + mt * 16 + row0 + r;
                if (node < n) {
                    float v = acc[mt][nt][r] + bias;
                    if (!RAW) v = v > 0.f ? v : 0.f;
                    if (OUT_BF16)
                        ((unsigned short*)outv)[(size_t)node * COUT + col] = f2bf(v);
                    else
                        ((float*)outv)[(size_t)node * COUT + col] = v;
                }
            }
        }
    }
}

// ---------------- launch ----------------

extern "C" void kernel_launch(void* const* d_in, const int* in_sizes, int n_in,
                              void* d_out, int out_size, void* d_ws, size_t ws_size,
                              hipStream_t stream) {
    const float* x0  = (const float*)d_in[0];
    const int*   ei  = (const int*)d_in[1];
    const float* wgt = (const float*)d_in[2];
    const float* sim = (const float*)d_in[3];
    const float *wr[3], *wi[3], *cb[3], *lw[3], *lb[3];
    for (int l = 0; l < 3; ++l) {
        wr[l] = (const float*)d_in[4 + 5 * l];
        wi[l] = (const float*)d_in[5 + 5 * l];
        cb[l] = (const float*)d_in[6 + 5 * l];
        lw[l] = (const float*)d_in[7 + 5 * l];
        lb[l] = (const float*)d_in[8 + 5 * l];
    }

    char* p = (char*)d_ws;
    auto alloc = [&](size_t bytes) -> void* {
        void* r = p;
        p += (bytes + 255) & ~(size_t)255;
        return r;
    };
    int*   off  = (int*)alloc((N_NODES + 1) * 4);
    int*   cnt  = (int*)alloc(N_NODES * 4);
    int*   bsum = (int*)alloc(256);
    uint2* edat = (uint2*)alloc((size_t)E_PAD_MAX * 8);
    unsigned short* xb    = (unsigned short*)alloc((size_t)N_NODES * 96 * 2);
    unsigned short* aggRb = (unsigned short*)alloc((size_t)N_NODES * 128 * 2);
    unsigned short* aggIb = (unsigned short*)alloc((size_t)N_NODES * 128 * 2);
    unsigned short* h1b   = (unsigned short*)alloc((size_t)N_NODES * 128 * 2);
    unsigned short* h2b   = (unsigned short*)alloc((size_t)N_NODES * 128 * 2);
    unsigned short* Yb    = (unsigned short*)alloc((size_t)N_NODES * 96 * 2);
    unsigned short* BT0   = (unsigned short*)alloc((size_t)128 * 288 * 2);
    unsigned short* BT1   = (unsigned short*)alloc((size_t)128 * 384 * 2);
    unsigned short* BT2   = (unsigned short*)alloc((size_t)96 * 128 * 2);
    float* outp = (float*)d_out;

    // CSR build (padded segments; edat pre-zeroed so pad slots are null edges)
    hipMemsetAsync(cnt, 0, N_NODES * 4, stream);
    hipMemsetAsync(edat, 0, (size_t)E_PAD_MAX * 8, stream);
    hist_kernel<<<(N_EDGES + 255) / 256, 256, 0, stream>>>(ei, cnt, N_EDGES);
    int nb = (N_NODES + 1023) / 1024;
    scan1<<<nb, 256, 0, stream>>>(cnt, off, bsum, N_NODES);
    scan2<<<1, 64, 0, stream>>>(bsum, nb);
    scan3<<<(N_NODES + 1 + 255) / 256, 256, 0, stream>>>(off, bsum, N_NODES, nb);
    hipMemsetAsync(cnt, 0, N_NODES * 4, stream);
    scatter_kernel<<<(N_EDGES + 255) / 256, 256, 0, stream>>>(ei, wgt, sim, off, cnt,
                                                              edat, N_EDGES);
    // prep
    convert_x<<<(N_NODES * 96 + 255) / 256, 256, 0, stream>>>(x0, xb, N_NODES);
    build_bt<<<(128 * 288 + 255) / 256, 256, 0, stream>>>(wr[0], wi[0], lw[0], BT0, 75, 96, 128);
    build_bt<<<(128 * 384 + 255) / 256, 256, 0, stream>>>(wr[1], wi[1], lw[1], BT1, 128, 128, 128);
    build_bty<<<(96 * 128 + 255) / 256, 256, 0, stream>>>(wr[2], wi[2], lw[2], BT2);

    int agrid = (N_NODES + 3) / 4;

    // layer 0: xb [N,96] -> h1b [N,128]
    agg_bf16<48><<<agrid, 256, 0, stream>>>((const uint32_tt*)xb, off, edat,
                                            (uint32_tt*)aggRb, (uint32_tt*)aggIb, N_NODES);
    gemm_mfma<96, 128, 64, 2, 2, 2, 4, true, false, 3>
        <<<(N_NODES + 63) / 64, 256, 0, stream>>>(aggRb, aggIb, xb, BT0, cb[0], lb[0],
                                                  h1b, N_NODES);
    // layer 1: h1b [N,128] -> h2b [N,128]
    agg_bf16<64><<<agrid, 256, 0, stream>>>((const uint32_tt*)h1b, off, edat,
                                            (uint32_tt*)aggRb, (uint32_tt*)aggIb, N_NODES);
    gemm_mfma<128, 128, 64, 2, 2, 2, 4, true, false, 3>
        <<<(N_NODES + 63) / 64, 256, 0, stream>>>(aggRb, aggIb, h1b, BT1, cb[1], lb[1],
                                                  h2b, N_NODES);
    // layer 2: Y = h2 @ [wr2|-wi2|lw2^T]  (N x 96), then fused agg+bias+relu
    gemm_mfma<128, 96, 64, 2, 2, 2, 3, true, true, 1>
        <<<(N_NODES + 63) / 64, 256, 0, stream>>>(h2b, h2b, h2b, BT2, cb[2], lb[2],
                                                  Yb, N_NODES);
    agg_out<<<agrid, 256, 0, stream>>>((const uint32_tt*)Yb, off, edat, cb[2], lb[2],
                                       outp, N_NODES);
}

// Round 7
// 297.721 us; speedup vs baseline: 1.1206x; 1.1206x over previous
//
#include <hip/hip_runtime.h>

#define N_NODES 50000
#define N_EDGES 600000
#define E_PAD_MAX (N_EDGES + N_NODES * 7)   // padded edge capacity

using bf16x8 = __attribute__((ext_vector_type(8))) short;
using f32x4  = __attribute__((ext_vector_type(4))) float;
typedef unsigned int uint32_tt;

__device__ __forceinline__ unsigned short f2bf(float f) {
    union { float f; unsigned int u; } v; v.f = f;
    unsigned int u = v.u;
    return (unsigned short)((u + 0x7fffu + ((u >> 16) & 1u)) >> 16);  // RNE
}
__device__ __forceinline__ float bf2f(unsigned int h16) {
    union { unsigned int u; float f; } v; v.u = h16 << 16;
    return v.f;
}

// ---------------- CSR build (degrees padded to multiple of 8) ----------------

__global__ void hist_kernel(const int* __restrict__ ei, int* __restrict__ cnt, int E) {
    int e = blockIdx.x * 256 + threadIdx.x;
    if (e < E) atomicAdd(&cnt[ei[E + e]], 1);
}

// scan over PADDED degrees: (deg+7)&~7
__global__ void scan1(const int* __restrict__ deg, int* __restrict__ out,
                      int* __restrict__ bsum, int n) {
    __shared__ int s[256];
    int t = threadIdx.x;
    int base = blockIdx.x * 1024 + t * 4;
    int v0 = (base + 0 < n) ? ((deg[base + 0] + 7) & ~7) : 0;
    int v1 = (base + 1 < n) ? ((deg[base + 1] + 7) & ~7) : 0;
    int v2 = (base + 2 < n) ? ((deg[base + 2] + 7) & ~7) : 0;
    int v3 = (base + 3 < n) ? ((deg[base + 3] + 7) & ~7) : 0;
    int tsum = v0 + v1 + v2 + v3;
    s[t] = tsum;
    __syncthreads();
    for (int off = 1; off < 256; off <<= 1) {
        int tmp = (t >= off) ? s[t - off] : 0;
        __syncthreads();
        s[t] += tmp;
        __syncthreads();
    }
    int excl = s[t] - tsum;
    if (base + 0 < n) out[base + 0] = excl;
    if (base + 1 < n) out[base + 1] = excl + v0;
    if (base + 2 < n) out[base + 2] = excl + v0 + v1;
    if (base + 3 < n) out[base + 3] = excl + v0 + v1 + v2;
    if (t == 255) bsum[blockIdx.x] = s[255];
}

__global__ void scan2(int* __restrict__ bsum, int nb) {
    if (threadIdx.x == 0 && blockIdx.x == 0) {
        int acc = 0;
        for (int i = 0; i < nb; ++i) { int v = bsum[i]; bsum[i] = acc; acc += v; }
        bsum[nb] = acc;   // total padded edge count
    }
}

__global__ void scan3(int* __restrict__ off, const int* __restrict__ bsum, int n, int nb) {
    int i = blockIdx.x * 256 + threadIdx.x;
    if (i < n) off[i] += bsum[i >> 10];
    if (i == n) off[n] = bsum[nb];
}

// 8-byte edge record: {src:u32, bf16(cr)|bf16(ci)<<16}; pad slots stay all-zero
// from the edat memset ({src=0, cr=0, ci=0} contributes exactly 0)
__global__ void scatter_kernel(const int* __restrict__ ei, const float* __restrict__ w,
                               const float* __restrict__ sim, const int* __restrict__ off,
                               int* __restrict__ cnt, uint2* __restrict__ edat, int E) {
    int e = blockIdx.x * 256 + threadIdx.x;
    if (e >= E) return;
    int s = ei[e], d = ei[E + e];
    int p = off[d] + atomicAdd(&cnt[d], 1);
    float wt = w[e];
    uint2 m;
    m.x = (unsigned)s;
    m.y = (uint32_tt)f2bf(wt * sim[2 * e]) |
          ((uint32_tt)f2bf(wt * sim[2 * e + 1]) << 16);
    edat[p] = m;
}

// ---------------- prep: x -> bf16 padded [N][96]; weight packs ----------------

__global__ void convert_x(const float* __restrict__ x0, unsigned short* __restrict__ xb, int n) {
    int i = blockIdx.x * 256 + threadIdx.x;
    if (i >= n * 96) return;
    int r = i / 96, c = i - r * 96;
    xb[i] = (c < 75) ? f2bf(x0[r * 75 + c]) : (unsigned short)0;
}

// BT[n][part*CINP + k] = {wr[k][n], -wi[k][n], lw[n][k]}  (bf16, zero-padded k>=CIN)
__global__ void build_bt(const float* __restrict__ wr, const float* __restrict__ wi,
                         const float* __restrict__ lw, unsigned short* __restrict__ BT,
                         int CIN, int CINP, int COUT) {
    int KTOT = 3 * CINP;
    int i = blockIdx.x * 256 + threadIdx.x;
    if (i >= COUT * KTOT) return;
    int nn = i / KTOT, k = i - nn * KTOT;
    int part = k / CINP, kk = k - part * CINP;
    float v = 0.f;
    if (kk < CIN) {
        if (part == 0)      v = wr[kk * COUT + nn];
        else if (part == 1) v = -wi[kk * COUT + nn];
        else                v = lw[nn * CIN + kk];
    }
    BT[i] = f2bf(v);
}

// layer-2 projection weights: BTy [96][128]: rows 0-31 wr2 cols, 32-63 -wi2
// cols, 64-95 lw2 rows  =>  Y = h2 @ [wr2 | -wi2 | lw2^T]
__global__ void build_bty(const float* __restrict__ wr, const float* __restrict__ wi,
                          const float* __restrict__ lw, unsigned short* __restrict__ BT) {
    int i = blockIdx.x * 256 + threadIdx.x;
    if (i >= 96 * 128) return;
    int nn = i >> 7, k = i & 127;
    float v;
    if (nn < 32)      v = wr[k * 32 + nn];
    else if (nn < 64) v = -wi[k * 32 + (nn - 32)];
    else              v = lw[(nn - 64) * 128 + k];
    BT[i] = f2bf(v);
}

// ---------------- aggregation: one wave per node, scalarized edge metadata ---
template <int CU2>  // uint32s per feature row (= CINP/2)
__global__ __launch_bounds__(256) void agg_bf16(
    const uint32_tt* __restrict__ x, const int* __restrict__ off,
    const uint2* __restrict__ edat, uint32_tt* __restrict__ aggR,
    uint32_tt* __restrict__ aggI, int n) {
    int wave = threadIdx.x >> 6;
    int lane = threadIdx.x & 63;
    int node = __builtin_amdgcn_readfirstlane(blockIdx.x * 4 + wave);
    if (node >= n) return;
    int lc = (CU2 == 64) ? lane : (lane < CU2 ? lane : CU2 - 1);  // clamped lane
    float arl = 0.f, arh = 0.f, ail = 0.f, aih = 0.f;
    int e0 = __builtin_amdgcn_readfirstlane(off[node]);
    int e1 = __builtin_amdgcn_readfirstlane(off[node + 1]);

    if (e0 < e1) {
        uint2 m[8];
#pragma unroll
        for (int j = 0; j < 8; ++j) m[j] = edat[e0 + j];
        for (int e = e0; e < e1; e += 8) {
            int sj[8]; float crj[8], cij[8];
#pragma unroll
            for (int j = 0; j < 8; ++j) {
                sj[j] = __builtin_amdgcn_readfirstlane((int)m[j].x);
                int pk = __builtin_amdgcn_readfirstlane((int)m[j].y);
                crj[j] = bf2f((unsigned)pk & 0xffffu);
                cij[j] = bf2f((unsigned)pk >> 16);
            }
            // 8 independent gathers, SGPR base + invariant lane offset
            uint32_tt w[8];
#pragma unroll
            for (int j = 0; j < 8; ++j) {
                const uint32_tt* rowp = x + (size_t)sj[j] * CU2;
                w[j] = rowp[lc];
            }
            // prefetch next batch's metadata while gathers are in flight
            if (e + 8 < e1) {
#pragma unroll
                for (int j = 0; j < 8; ++j) m[j] = edat[e + 8 + j];
            }
#pragma unroll
            for (int j = 0; j < 8; ++j) {
                float lo = bf2f(w[j] & 0xffffu), hi = bf2f(w[j] >> 16);
                arl += crj[j] * lo; arh += crj[j] * hi;
                ail += cij[j] * lo; aih += cij[j] * hi;
            }
        }
    }
    if (lane < CU2) {
        aggR[(size_t)node * CU2 + lane] = (uint32_tt)f2bf(arl) | ((uint32_tt)f2bf(arh) << 16);
        aggI[(size_t)node * CU2 + lane] = (uint32_tt)f2bf(ail) | ((uint32_tt)f2bf(aih) << 16);
    }
}

// ---------------- layer-2 fused aggregate + bias + relu + store --------------
// Y [n][48 dwords]: dwords 0-15 = Yr (32 cols bf16), 16-31 = Yin, 32-47 = lin.
// Structure mirrors agg_bf16 exactly (known-good codegen): one edge per
// iteration, SGPR base + invariant lane offset, lanes 0-15 weight cr,
// 16-31 weight ci, 32-63 clamped duplicates (discarded).
__global__ __launch_bounds__(256) void agg_out(
    const uint32_tt* __restrict__ Y, const int* __restrict__ off,
    const uint2* __restrict__ edat, const float* __restrict__ cb,
    const float* __restrict__ lb, float* __restrict__ out, int n) {
    int wave = threadIdx.x >> 6;
    int lane = threadIdx.x & 63;
    int node = __builtin_amdgcn_readfirstlane(blockIdx.x * 4 + wave);
    if (node >= n) return;
    int lc = (lane < 32) ? lane : 31;        // clamped lane offset
    int usei = (lane >> 4) & 1;              // 0: cr, 1: ci
    float alo = 0.f, ahi = 0.f;
    int e0 = __builtin_amdgcn_readfirstlane(off[node]);
    int e1 = __builtin_amdgcn_readfirstlane(off[node + 1]);

    if (e0 < e1) {
        uint2 m[8];
#pragma unroll
        for (int j = 0; j < 8; ++j) m[j] = edat[e0 + j];
        for (int e = e0; e < e1; e += 8) {
            int sj[8]; float crj[8], cij[8];
#pragma unroll
            for (int j = 0; j < 8; ++j) {
                sj[j] = __builtin_amdgcn_readfirstlane((int)m[j].x);
                int pk = __builtin_amdgcn_readfirstlane((int)m[j].y);
                crj[j] = bf2f((unsigned)pk & 0xffffu);
                cij[j] = bf2f((unsigned)pk >> 16);
            }
            uint32_tt w[8];
#pragma unroll
            for (int j = 0; j < 8; ++j) {
                const uint32_tt* rowp = Y + (size_t)sj[j] * 48;
                w[j] = rowp[lc];
            }
            if (e + 8 < e1) {
#pragma unroll
                for (int j = 0; j < 8; ++j) m[j] = edat[e + 8 + j];
            }
#pragma unroll
            for (int j = 0; j < 8; ++j) {
                float c = usei ? cij[j] : crj[j];
                float lo = bf2f(w[j] & 0xffffu), hi = bf2f(w[j] >> 16);
                alo += c * lo; ahi += c * hi;
            }
        }
    }
    // lane L (<16) holds cr*Yr for cols {2L,2L+1}; lane L+16 holds ci*Yin.
    alo += __shfl_xor(alo, 16);
    ahi += __shfl_xor(ahi, 16);
    if (lane < 16) {
        uint32_tt lin = Y[(size_t)node * 48 + 32 + lane];
        int c0 = 2 * lane, c1 = 2 * lane + 1;
        float v0 = alo + bf2f(lin & 0xffffu) + cb[c0] + lb[c0];
        float v1 = ahi + bf2f(lin >> 16) + cb[c1] + lb[c1];
        float2 r;
        r.x = v0 > 0.f ? v0 : 0.f;
        r.y = v1 > 0.f ? v1 : 0.f;
        ((float2*)out)[(size_t)node * 16 + lane] = r;
    }
}

// ---------------- bf16 MFMA GEMM ---------------------------------------------
// PARTS=3: out = relu([A0|A1|A2] @ BT^T + cb + lb); PARTS=1, RAW: out = A0 @ BT^T
template <int CINP, int COUT, int BM, int WM, int WN, int MT, int NT,
          bool OUT_BF16, bool RAW, int PARTS>
__global__ __launch_bounds__(256) void gemm_mfma(
    const unsigned short* __restrict__ A0, const unsigned short* __restrict__ A1,
    const unsigned short* __restrict__ A2, const unsigned short* __restrict__ BT,
    const float* __restrict__ cb, const float* __restrict__ lb,
    void* __restrict__ outv, int n) {
    constexpr int PK = 40;              // padded k-stride (bf16): 80B rows -> 2-way banks
    constexpr int KTOT = PARTS * CINP;
    constexpr int NCH = KTOT / 32;      // K chunks
    constexpr int CPP = CINP / 32;      // chunks per part
    __shared__ unsigned short sA[BM][PK];
    __shared__ unsigned short sB[COUT][PK];

    int t = threadIdx.x;
    int lane = t & 63, wave = t >> 6;
    int wm = wave / WN, wn = wave % WN;
    int ml = lane & 15, kh = lane >> 4;   // kh in [0,4)
    int node0 = blockIdx.x * BM;

    const unsigned short* Asrc[3] = {A0, A1, A2};

    f32x4 acc[MT][NT];
#pragma unroll
    for (int mt = 0; mt < MT; ++mt)
#pragma unroll
        for (int nt = 0; nt < NT; ++nt) acc[mt][nt] = (f32x4){0.f, 0.f, 0.f, 0.f};

    for (int c = 0; c < NCH; ++c) {
        int part = (PARTS == 1) ? 0 : (c / CPP);
        int kk = (c - part * CPP) * 32;
        const unsigned short* __restrict__ Ap = Asrc[part];
        __syncthreads();
#pragma unroll
        for (int i = t; i < BM * 4; i += 256) {
            int r = i >> 2, q = i & 3;
            int node = node0 + r;
            if (node >= n) node = n - 1;  // clamp: garbage rows never written out
            *(uint4*)&sA[r][q * 8] =
                *(const uint4*)(Ap + (size_t)node * CINP + kk + q * 8);
        }
#pragma unroll
        for (int i = t; i < COUT * 4; i += 256) {
            int r = i >> 2, q = i & 3;
            *(uint4*)&sB[r][q * 8] =
                *(const uint4*)(BT + (size_t)r * KTOT + c * 32 + q * 8);
        }
        __syncthreads();
        bf16x8 af[MT], bfr[NT];
#pragma unroll
        for (int mt = 0; mt < MT; ++mt)
            af[mt] = *(const bf16x8*)&sA[wm * (MT * 16) + mt * 16 + ml][kh * 8];
#pragma unroll
        for (int nt = 0; nt < NT; ++nt)
            bfr[nt] = *(const bf16x8*)&sB[wn * (NT * 16) + nt * 16 + ml][kh * 8];
#pragma unroll
        for (int mt = 0; mt < MT; ++mt)
#pragma unroll
            for (int nt = 0; nt < NT; ++nt)
                acc[mt][nt] = __builtin_amdgcn_mfma_f32_16x16x32_bf16(
                    af[mt], bfr[nt], acc[mt][nt], 0, 0, 0);
    }

    // epilogue: C/D layout col=lane&15, row=(lane>>4)*4+reg  [m89-verified]
    int row0 = kh * 4;
#pragma unroll
    for (int nt = 0; nt < NT; ++nt) {
        int col = wn * (NT * 16) + nt * 16 + ml;
        float bias = RAW ? 0.f : (cb[col] + lb[col]);
#pragma unroll
        for (int mt = 0; mt < MT; ++mt) {
#pragma unroll
            for (int r = 0; r < 4; ++r) {
                int node = node0 + wm * (MT * 16) + mt * 16 + row0 + r;
                if (node < n) {
                    float v = acc[mt][nt][r] + bias;
                    if (!RAW) v = v > 0.f ? v : 0.f;
                    if (OUT_BF16)
                        ((unsigned short*)outv)[(size_t)node * COUT + col] = f2bf(v);
                    else
                        ((float*)outv)[(size_t)node * COUT + col] = v;
                }
            }
        }
    }
}

// ---------------- launch ----------------

extern "C" void kernel_launch(void* const* d_in, const int* in_sizes, int n_in,
                              void* d_out, int out_size, void* d_ws, size_t ws_size,
                              hipStream_t stream) {
    const float* x0  = (const float*)d_in[0];
    const int*   ei  = (const int*)d_in[1];
    const float* wgt = (const float*)d_in[2];
    const float* sim = (const float*)d_in[3];
    const float *wr[3], *wi[3], *cb[3], *lw[3], *lb[3];
    for (int l = 0; l < 3; ++l) {
        wr[l] = (const float*)d_in[4 + 5 * l];
        wi[l] = (const float*)d_in[5 + 5 * l];
        cb[l] = (const float*)d_in[6 + 5 * l];
        lw[l] = (const float*)d_in[7 + 5 * l];
        lb[l] = (const float*)d_in[8 + 5 * l];
    }

    char* p = (char*)d_ws;
    auto alloc = [&](size_t bytes) -> void* {
        void* r = p;
        p += (bytes + 255) & ~(size_t)255;
        return r;
    };
    int*   off  = (int*)alloc((N_NODES + 1) * 4);
    int*   cnt  = (int*)alloc(N_NODES * 4);
    int*   bsum = (int*)alloc(256);
    uint2* edat = (uint2*)alloc((size_t)E_PAD_MAX * 8);
    unsigned short* xb    = (unsigned short*)alloc((size_t)N_NODES * 96 * 2);
    unsigned short* aggRb = (unsigned short*)alloc((size_t)N_NODES * 128 * 2);
    unsigned short* aggIb = (unsigned short*)alloc((size_t)N_NODES * 128 * 2);
    unsigned short* h1b   = (unsigned short*)alloc((size_t)N_NODES * 128 * 2);
    unsigned short* h2b   = (unsigned short*)alloc((size_t)N_NODES * 128 * 2);
    unsigned short* Yb    = (unsigned short*)alloc((size_t)N_NODES * 96 * 2);
    unsigned short* BT0   = (unsigned short*)alloc((size_t)128 * 288 * 2);
    unsigned short* BT1   = (unsigned short*)alloc((size_t)128 * 384 * 2);
    unsigned short* BT2   = (unsigned short*)alloc((size_t)96 * 128 * 2);
    float* outp = (float*)d_out;

    // CSR build (padded segments; edat pre-zeroed so pad slots are null edges)
    hipMemsetAsync(cnt, 0, N_NODES * 4, stream);
    hipMemsetAsync(edat, 0, (size_t)E_PAD_MAX * 8, stream);
    hist_kernel<<<(N_EDGES + 255) / 256, 256, 0, stream>>>(ei, cnt, N_EDGES);
    int nb = (N_NODES + 1023) / 1024;
    scan1<<<nb, 256, 0, stream>>>(cnt, off, bsum, N_NODES);
    scan2<<<1, 64, 0, stream>>>(bsum, nb);
    scan3<<<(N_NODES + 1 + 255) / 256, 256, 0, stream>>>(off, bsum, N_NODES, nb);
    hipMemsetAsync(cnt, 0, N_NODES * 4, stream);
    scatter_kernel<<<(N_EDGES + 255) / 256, 256, 0, stream>>>(ei, wgt, sim, off, cnt,
                                                              edat, N_EDGES);
    // prep
    convert_x<<<(N_NODES * 96 + 255) / 256, 256, 0, stream>>>(x0, xb, N_NODES);
    build_bt<<<(128 * 288 + 255) / 256, 256, 0, stream>>>(wr[0], wi[0], lw[0], BT0, 75, 96, 128);
    build_bt<<<(128 * 384 + 255) / 256, 256, 0, stream>>>(wr[1], wi[1], lw[1], BT1, 128, 128, 128);
    build_bty<<<(96 * 128 + 255) / 256, 256, 0, stream>>>(wr[2], wi[2], lw[2], BT2);

    int agrid = (N_NODES + 3) / 4;

    // layer 0: xb [N,96] -> h1b [N,128]
    agg_bf16<48><<<agrid, 256, 0, stream>>>((const uint32_tt*)xb, off, edat,
                                            (uint32_tt*)aggRb, (uint32_tt*)aggIb, N_NODES);
    gemm_mfma<96, 128, 64, 2, 2, 2, 4, true, false, 3>
        <<<(N_NODES + 63) / 64, 256, 0, stream>>>(aggRb, aggIb, xb, BT0, cb[0], lb[0],
                                                  h1b, N_NODES);
    // layer 1: h1b [N,128] -> h2b [N,128]
    agg_bf16<64><<<agrid, 256, 0, stream>>>((const uint32_tt*)h1b, off, edat,
                                            (uint32_tt*)aggRb, (uint32_tt*)aggIb, N_NODES);
    gemm_mfma<128, 128, 64, 2, 2, 2, 4, true, false, 3>
        <<<(N_NODES + 63) / 64, 256, 0, stream>>>(aggRb, aggIb, h1b, BT1, cb[1], lb[1],
                                                  h2b, N_NODES);
    // layer 2: Y = h2 @ [wr2|-wi2|lw2^T]  (N x 96), then fused agg+bias+relu
    gemm_mfma<128, 96, 64, 2, 2, 2, 3, true, true, 1>
        <<<(N_NODES + 63) / 64, 256, 0, stream>>>(h2b, h2b, h2b, BT2, cb[2], lb[2],
                                                  Yb, N_NODES);
    agg_out<<<agrid, 256, 0, stream>>>((const uint32_tt*)Yb, off, edat, cb[2], lb[2],
                                       outp, N_NODES);
}

// Round 8
// 294.906 us; speedup vs baseline: 1.1313x; 1.0095x over previous
//
#include <hip/hip_runtime.h>

#define N_NODES 50000
#define N_EDGES 600000
#define E_PAD_MAX (N_EDGES + N_NODES * 7)   // padded edge capacity

using bf16x8 = __attribute__((ext_vector_type(8))) short;
using f32x4  = __attribute__((ext_vector_type(4))) float;
typedef unsigned int uint32_tt;

__device__ __forceinline__ unsigned short f2bf(float f) {
    union { float f; unsigned int u; } v; v.f = f;
    unsigned int u = v.u;
    return (unsigned short)((u + 0x7fffu + ((u >> 16) & 1u)) >> 16);  // RNE
}
__device__ __forceinline__ float bf2f(unsigned int h16) {
    union { unsigned int u; float f; } v; v.u = h16 << 16;
    return v.f;
}

// ---------------- CSR build (degrees padded to multiple of 8) ----------------

__global__ void hist_kernel(const int* __restrict__ ei, int* __restrict__ cnt, int E) {
    int e = blockIdx.x * 256 + threadIdx.x;
    if (e < E) atomicAdd(&cnt[ei[E + e]], 1);
}

// scan over PADDED degrees: (deg+7)&~7
__global__ void scan1(const int* __restrict__ deg, int* __restrict__ out,
                      int* __restrict__ bsum, int n) {
    __shared__ int s[256];
    int t = threadIdx.x;
    int base = blockIdx.x * 1024 + t * 4;
    int v0 = (base + 0 < n) ? ((deg[base + 0] + 7) & ~7) : 0;
    int v1 = (base + 1 < n) ? ((deg[base + 1] + 7) & ~7) : 0;
    int v2 = (base + 2 < n) ? ((deg[base + 2] + 7) & ~7) : 0;
    int v3 = (base + 3 < n) ? ((deg[base + 3] + 7) & ~7) : 0;
    int tsum = v0 + v1 + v2 + v3;
    s[t] = tsum;
    __syncthreads();
    for (int off = 1; off < 256; off <<= 1) {
        int tmp = (t >= off) ? s[t - off] : 0;
        __syncthreads();
        s[t] += tmp;
        __syncthreads();
    }
    int excl = s[t] - tsum;
    if (base + 0 < n) out[base + 0] = excl;
    if (base + 1 < n) out[base + 1] = excl + v0;
    if (base + 2 < n) out[base + 2] = excl + v0 + v1;
    if (base + 3 < n) out[base + 3] = excl + v0 + v1 + v2;
    if (t == 255) bsum[blockIdx.x] = s[255];
}

__global__ void scan2(int* __restrict__ bsum, int nb) {
    if (threadIdx.x == 0 && blockIdx.x == 0) {
        int acc = 0;
        for (int i = 0; i < nb; ++i) { int v = bsum[i]; bsum[i] = acc; acc += v; }
        bsum[nb] = acc;   // total padded edge count
    }
}

// add block offsets; also zero cnt for scatter's cursors (saves a memset)
__global__ void scan3(int* __restrict__ off, const int* __restrict__ bsum,
                      int* __restrict__ cnt, int n, int nb) {
    int i = blockIdx.x * 256 + threadIdx.x;
    if (i < n) { off[i] += bsum[i >> 10]; cnt[i] = 0; }
    if (i == n) off[n] = bsum[nb];
}

// 8-byte edge record: {src:u32, bf16(cr)|bf16(ci)<<16}; pad slots stay all-zero
// from the edat memset ({src=0, cr=0, ci=0} contributes exactly 0)
__global__ void scatter_kernel(const int* __restrict__ ei, const float* __restrict__ w,
                               const float* __restrict__ sim, const int* __restrict__ off,
                               int* __restrict__ cnt, uint2* __restrict__ edat, int E) {
    int e = blockIdx.x * 256 + threadIdx.x;
    if (e >= E) return;
    int s = ei[e], d = ei[E + e];
    int p = off[d] + atomicAdd(&cnt[d], 1);
    float wt = w[e];
    uint2 m;
    m.x = (unsigned)s;
    m.y = (uint32_tt)f2bf(wt * sim[2 * e]) |
          ((uint32_tt)f2bf(wt * sim[2 * e + 1]) << 16);
    edat[p] = m;
}

// ---------------- merged prep: x->bf16 [N][96]; 3 weight packs ----------------
// BT0/BT1: [COUT][3*CINP] = {wr, -wi, lw-row}; BT2: [96][128] = [wr2|-wi2|lw2^T]
__global__ void prep_kernel(
    const float* __restrict__ x0, unsigned short* __restrict__ xb,
    const float* __restrict__ wr0, const float* __restrict__ wi0,
    const float* __restrict__ lw0, unsigned short* __restrict__ BT0,
    const float* __restrict__ wr1, const float* __restrict__ wi1,
    const float* __restrict__ lw1, unsigned short* __restrict__ BT1,
    const float* __restrict__ wr2, const float* __restrict__ wi2,
    const float* __restrict__ lw2, unsigned short* __restrict__ BT2, int n) {
    int i = blockIdx.x * 256 + threadIdx.x;
    int nconv = n * 96;
    if (i < nconv) {
        int r = i / 96, c = i - r * 96;
        xb[i] = (c < 75) ? f2bf(x0[r * 75 + c]) : (unsigned short)0;
        return;
    }
    i -= nconv;
    if (i < 128 * 288) {   // BT0: CIN=75 CINP=96 COUT=128
        int nn = i / 288, k = i - nn * 288;
        int part = k / 96, kk = k - part * 96;
        float v = 0.f;
        if (kk < 75) {
            if (part == 0)      v = wr0[kk * 128 + nn];
            else if (part == 1) v = -wi0[kk * 128 + nn];
            else                v = lw0[nn * 75 + kk];
        }
        BT0[i] = f2bf(v);
        return;
    }
    i -= 128 * 288;
    if (i < 128 * 384) {   // BT1: CIN=CINP=128 COUT=128
        int nn = i / 384, k = i - nn * 384;
        int part = k >> 7, kk = k & 127;
        float v;
        if (part == 0)      v = wr1[kk * 128 + nn];
        else if (part == 1) v = -wi1[kk * 128 + nn];
        else                v = lw1[nn * 128 + kk];
        BT1[i] = f2bf(v);
        return;
    }
    i -= 128 * 384;
    if (i < 96 * 128) {    // BT2 (Y-projection)
        int nn = i >> 7, k = i & 127;
        float v;
        if (nn < 32)      v = wr2[k * 32 + nn];
        else if (nn < 64) v = -wi2[k * 32 + (nn - 32)];
        else              v = lw2[(nn - 64) * 128 + k];
        BT2[i] = f2bf(v);
    }
}

// ---------------- aggregation: one wave per node, scalarized edge metadata ---
template <int CU2>  // uint32s per feature row (= CINP/2)
__global__ __launch_bounds__(256) void agg_bf16(
    const uint32_tt* __restrict__ x, const int* __restrict__ off,
    const uint2* __restrict__ edat, uint32_tt* __restrict__ aggR,
    uint32_tt* __restrict__ aggI, int n) {
    int wave = threadIdx.x >> 6;
    int lane = threadIdx.x & 63;
    int node = __builtin_amdgcn_readfirstlane(blockIdx.x * 4 + wave);
    if (node >= n) return;
    int lc = (CU2 == 64) ? lane : (lane < CU2 ? lane : CU2 - 1);  // clamped lane
    float arl = 0.f, arh = 0.f, ail = 0.f, aih = 0.f;
    int e0 = __builtin_amdgcn_readfirstlane(off[node]);
    int e1 = __builtin_amdgcn_readfirstlane(off[node + 1]);

    if (e0 < e1) {
        uint2 m[8];
#pragma unroll
        for (int j = 0; j < 8; ++j) m[j] = edat[e0 + j];
        for (int e = e0; e < e1; e += 8) {
            int sj[8]; float crj[8], cij[8];
#pragma unroll
            for (int j = 0; j < 8; ++j) {
                sj[j] = __builtin_amdgcn_readfirstlane((int)m[j].x);
                int pk = __builtin_amdgcn_readfirstlane((int)m[j].y);
                crj[j] = bf2f((unsigned)pk & 0xffffu);
                cij[j] = bf2f((unsigned)pk >> 16);
            }
            // 8 independent gathers, SGPR base + invariant lane offset
            uint32_tt w[8];
#pragma unroll
            for (int j = 0; j < 8; ++j) {
                const uint32_tt* rowp = x + (size_t)sj[j] * CU2;
                w[j] = rowp[lc];
            }
            // prefetch next batch's metadata while gathers are in flight
            if (e + 8 < e1) {
#pragma unroll
                for (int j = 0; j < 8; ++j) m[j] = edat[e + 8 + j];
            }
#pragma unroll
            for (int j = 0; j < 8; ++j) {
                float lo = bf2f(w[j] & 0xffffu), hi = bf2f(w[j] >> 16);
                arl += crj[j] * lo; arh += crj[j] * hi;
                ail += cij[j] * lo; aih += cij[j] * hi;
            }
        }
    }
    if (lane < CU2) {
        aggR[(size_t)node * CU2 + lane] = (uint32_tt)f2bf(arl) | ((uint32_tt)f2bf(arh) << 16);
        aggI[(size_t)node * CU2 + lane] = (uint32_tt)f2bf(ail) | ((uint32_tt)f2bf(aih) << 16);
    }
}

// ---------------- layer-2 fused aggregate + bias + relu + store --------------
// Y [n][48 dwords]: dwords 0-15 = Yr (32 cols bf16), 16-31 = Yin, 32-47 = lin.
__global__ __launch_bounds__(256) void agg_out(
    const uint32_tt* __restrict__ Y, const int* __restrict__ off,
    const uint2* __restrict__ edat, const float* __restrict__ cb,
    const float* __restrict__ lb, float* __restrict__ out, int n) {
    int wave = threadIdx.x >> 6;
    int lane = threadIdx.x & 63;
    int node = __builtin_amdgcn_readfirstlane(blockIdx.x * 4 + wave);
    if (node >= n) return;
    int lc = (lane < 32) ? lane : 31;        // clamped lane offset
    int usei = (lane >> 4) & 1;              // 0: cr, 1: ci
    float alo = 0.f, ahi = 0.f;
    int e0 = __builtin_amdgcn_readfirstlane(off[node]);
    int e1 = __builtin_amdgcn_readfirstlane(off[node + 1]);

    if (e0 < e1) {
        uint2 m[8];
#pragma unroll
        for (int j = 0; j < 8; ++j) m[j] = edat[e0 + j];
        for (int e = e0; e < e1; e += 8) {
            int sj[8]; float crj[8], cij[8];
#pragma unroll
            for (int j = 0; j < 8; ++j) {
                sj[j] = __builtin_amdgcn_readfirstlane((int)m[j].x);
                int pk = __builtin_amdgcn_readfirstlane((int)m[j].y);
                crj[j] = bf2f((unsigned)pk & 0xffffu);
                cij[j] = bf2f((unsigned)pk >> 16);
            }
            uint32_tt w[8];
#pragma unroll
            for (int j = 0; j < 8; ++j) {
                const uint32_tt* rowp = Y + (size_t)sj[j] * 48;
                w[j] = rowp[lc];
            }
            if (e + 8 < e1) {
#pragma unroll
                for (int j = 0; j < 8; ++j) m[j] = edat[e + 8 + j];
            }
#pragma unroll
            for (int j = 0; j < 8; ++j) {
                float c = usei ? cij[j] : crj[j];
                float lo = bf2f(w[j] & 0xffffu), hi = bf2f(w[j] >> 16);
                alo += c * lo; ahi += c * hi;
            }
        }
    }
    alo += __shfl_xor(alo, 16);
    ahi += __shfl_xor(ahi, 16);
    if (lane < 16) {
        uint32_tt lin = Y[(size_t)node * 48 + 32 + lane];
        int c0 = 2 * lane, c1 = 2 * lane + 1;
        float v0 = alo + bf2f(lin & 0xffffu) + cb[c0] + lb[c0];
        float v1 = ahi + bf2f(lin >> 16) + cb[c1] + lb[c1];
        float2 r;
        r.x = v0 > 0.f ? v0 : 0.f;
        r.y = v1 > 0.f ? v1 : 0.f;
        ((float2*)out)[(size_t)node * 16 + lane] = r;
    }
}

// ---------------- bf16 MFMA GEMM ---------------------------------------------
// PARTS=3: out = relu([A0|A1|A2] @ BT^T + cb + lb); PARTS=1, RAW: out = A0 @ BT^T
// Block tile BM x COUT, 4 waves (WM x WN), wave tile (MT*16) x (NT*16).
template <int CINP, int COUT, int BM, int WM, int WN, int MT, int NT,
          bool OUT_BF16, bool RAW, int PARTS>
__global__ __launch_bounds__(256) void gemm_mfma(
    const unsigned short* __restrict__ A0, const unsigned short* __restrict__ A1,
    const unsigned short* __restrict__ A2, const unsigned short* __restrict__ BT,
    const float* __restrict__ cb, const float* __restrict__ lb,
    void* __restrict__ outv, int n) {
    constexpr int PK = 40;              // padded k-stride (bf16): 80B rows -> 2-way banks
    constexpr int KTOT = PARTS * CINP;
    constexpr int NCH = KTOT / 32;      // K chunks
    constexpr int CPP = CINP / 32;      // chunks per part
    __shared__ unsigned short sA[BM][PK];
    __shared__ unsigned short sB[COUT][PK];

    int t = threadIdx.x;
    int lane = t & 63, wave = t >> 6;
    int wm = wave / WN, wn = wave % WN;
    int ml = lane & 15, kh = lane >> 4;   // kh in [0,4)
    int node0 = blockIdx.x * BM;

    const unsigned short* Asrc[3] = {A0, A1, A2};

    f32x4 acc[MT][NT];
#pragma unroll
    for (int mt = 0; mt < MT; ++mt)
#pragma unroll
        for (int nt = 0; nt < NT; ++nt) acc[mt][nt] = (f32x4){0.f, 0.f, 0.f, 0.f};

    for (int c = 0; c < NCH; ++c) {
        int part = (PARTS == 1) ? 0 : (c / CPP);
        int kk = (c - part * CPP) * 32;
        const unsigned short* __restrict__ Ap = Asrc[part];
        __syncthreads();
#pragma unroll
        for (int i = t; i < BM * 4; i += 256) {
            int r = i >> 2, q = i & 3;
            int node = node0 + r;
            if (node >= n) node = n - 1;  // clamp: garbage rows never written out
            *(uint4*)&sA[r][q * 8] =
                *(const uint4*)(Ap + (size_t)node * CINP + kk + q * 8);
        }
#pragma unroll
        for (int i = t; i < COUT * 4; i += 256) {
            int r = i >> 2, q = i & 3;
            *(uint4*)&sB[r][q * 8] =
                *(const uint4*)(BT + (size_t)r * KTOT + c * 32 + q * 8);
        }
        __syncthreads();
        bf16x8 af[MT], bfr[NT];
#pragma unroll
        for (int mt = 0; mt < MT; ++mt)
            af[mt] = *(const bf16x8*)&sA[wm * (MT * 16) + mt * 16 + ml][kh * 8];
#pragma unroll
        for (int nt = 0; nt < NT; ++nt)
            bfr[nt] = *(const bf16x8*)&sB[wn * (NT * 16) + nt * 16 + ml][kh * 8];
#pragma unroll
        for (int mt = 0; mt < MT; ++mt)
#pragma unroll
            for (int nt = 0; nt < NT; ++nt)
                acc[mt][nt] = __builtin_amdgcn_mfma_f32_16x16x32_bf16(
                    af[mt], bfr[nt], acc[mt][nt], 0, 0, 0);
    }

    // epilogue: C/D layout col=lane&15, row=(lane>>4)*4+reg  [m89-verified]
    int row0 = kh * 4;
#pragma unroll
    for (int nt = 0; nt < NT; ++nt) {
        int col = wn * (NT * 16) + nt * 16 + ml;
        float bias = RAW ? 0.f : (cb[col] + lb[col]);
#pragma unroll
        for (int mt = 0; mt < MT; ++mt) {
#pragma unroll
            for (int r = 0; r < 4; ++r) {
                int node = node0 + wm * (MT * 16) + mt * 16 + row0 + r;
                if (node < n) {
                    float v = acc[mt][nt][r] + bias;
                    if (!RAW) v = v > 0.f ? v : 0.f;
                    if (OUT_BF16)
                        ((unsigned short*)outv)[(size_t)node * COUT + col] = f2bf(v);
                    else
                        ((float*)outv)[(size_t)node * COUT + col] = v;
                }
            }
        }
    }
}

// ---------------- launch ----------------

extern "C" void kernel_launch(void* const* d_in, const int* in_sizes, int n_in,
                              void* d_out, int out_size, void* d_ws, size_t ws_size,
                              hipStream_t stream) {
    const float* x0  = (const float*)d_in[0];
    const int*   ei  = (const int*)d_in[1];
    const float* wgt = (const float*)d_in[2];
    const float* sim = (const float*)d_in[3];
    const float *wr[3], *wi[3], *cb[3], *lw[3], *lb[3];
    for (int l = 0; l < 3; ++l) {
        wr[l] = (const float*)d_in[4 + 5 * l];
        wi[l] = (const float*)d_in[5 + 5 * l];
        cb[l] = (const float*)d_in[6 + 5 * l];
        lw[l] = (const float*)d_in[7 + 5 * l];
        lb[l] = (const float*)d_in[8 + 5 * l];
    }

    char* p = (char*)d_ws;
    auto alloc = [&](size_t bytes) -> void* {
        void* r = p;
        p += (bytes + 255) & ~(size_t)255;
        return r;
    };
    int*   off  = (int*)alloc((N_NODES + 1) * 4);
    int*   cnt  = (int*)alloc(N_NODES * 4);
    int*   bsum = (int*)alloc(256);
    uint2* edat = (uint2*)alloc((size_t)E_PAD_MAX * 8);
    unsigned short* xb    = (unsigned short*)alloc((size_t)N_NODES * 96 * 2);
    unsigned short* aggRb = (unsigned short*)alloc((size_t)N_NODES * 128 * 2);
    unsigned short* aggIb = (unsigned short*)alloc((size_t)N_NODES * 128 * 2);
    unsigned short* h1b   = (unsigned short*)alloc((size_t)N_NODES * 128 * 2);
    unsigned short* h2b   = (unsigned short*)alloc((size_t)N_NODES * 128 * 2);
    unsigned short* Yb    = (unsigned short*)alloc((size_t)N_NODES * 96 * 2);
    unsigned short* BT0   = (unsigned short*)alloc((size_t)128 * 288 * 2);
    unsigned short* BT1   = (unsigned short*)alloc((size_t)128 * 384 * 2);
    unsigned short* BT2   = (unsigned short*)alloc((size_t)96 * 128 * 2);
    float* outp = (float*)d_out;

    // CSR build (padded segments; edat pre-zeroed so pad slots are null edges)
    hipMemsetAsync(cnt, 0, N_NODES * 4, stream);
    hipMemsetAsync(edat, 0, (size_t)E_PAD_MAX * 8, stream);
    hist_kernel<<<(N_EDGES + 255) / 256, 256, 0, stream>>>(ei, cnt, N_EDGES);
    int nb = (N_NODES + 1023) / 1024;
    scan1<<<nb, 256, 0, stream>>>(cnt, off, bsum, N_NODES);
    scan2<<<1, 64, 0, stream>>>(bsum, nb);
    scan3<<<(N_NODES + 1 + 255) / 256, 256, 0, stream>>>(off, bsum, cnt, N_NODES, nb);
    scatter_kernel<<<(N_EDGES + 255) / 256, 256, 0, stream>>>(ei, wgt, sim, off, cnt,
                                                              edat, N_EDGES);
    // merged prep
    {
        int total = N_NODES * 96 + 128 * 288 + 128 * 384 + 96 * 128;
        prep_kernel<<<(total + 255) / 256, 256, 0, stream>>>(
            x0, xb, wr[0], wi[0], lw[0], BT0, wr[1], wi[1], lw[1], BT1,
            wr[2], wi[2], lw[2], BT2, N_NODES);
    }

    int agrid = (N_NODES + 3) / 4;

    // layer 0: xb [N,96] -> h1b [N,128]
    agg_bf16<48><<<agrid, 256, 0, stream>>>((const uint32_tt*)xb, off, edat,
                                            (uint32_tt*)aggRb, (uint32_tt*)aggIb, N_NODES);
    gemm_mfma<96, 128, 128, 2, 2, 4, 4, true, false, 3>
        <<<(N_NODES + 127) / 128, 256, 0, stream>>>(aggRb, aggIb, xb, BT0, cb[0], lb[0],
                                                    h1b, N_NODES);
    // layer 1: h1b [N,128] -> h2b [N,128]
    agg_bf16<64><<<agrid, 256, 0, stream>>>((const uint32_tt*)h1b, off, edat,
                                            (uint32_tt*)aggRb, (uint32_tt*)aggIb, N_NODES);
    gemm_mfma<128, 128, 128, 2, 2, 4, 4, true, false, 3>
        <<<(N_NODES + 127) / 128, 256, 0, stream>>>(aggRb, aggIb, h1b, BT1, cb[1], lb[1],
                                                    h2b, N_NODES);
    // layer 2: Y = h2 @ [wr2|-wi2|lw2^T]  (N x 96), then fused agg+bias+relu
    gemm_mfma<128, 96, 128, 2, 2, 4, 3, true, true, 1>
        <<<(N_NODES + 127) / 128, 256, 0, stream>>>(h2b, h2b, h2b, BT2, cb[2], lb[2],
                                                    Yb, N_NODES);
    agg_out<<<agrid, 256, 0, stream>>>((const uint32_tt*)Yb, off, edat, cb[2], lb[2],
                                       outp, N_NODES);
}